// Round 1
// baseline (358.931 us; speedup 1.0000x reference)
//
#include <hip/hip_runtime.h>

typedef __bf16 bf16;
typedef __bf16 bf16x4 __attribute__((ext_vector_type(4)));
typedef __bf16 bf16x8 __attribute__((ext_vector_type(8)));
typedef float f32x4 __attribute__((ext_vector_type(4)));

#define AS1C(p) ((const __attribute__((address_space(1))) void*)(p))
#define AS3(p)  ((__attribute__((address_space(3))) void*)(p))

// ---------------- transpose fp32 (R x C) -> bf16 (C x R) ----------------
__global__ __launch_bounds__(256) void transpose_cast(
    const float* __restrict__ in, bf16* __restrict__ out, int R, int C)
{
    __shared__ float tile[32][33];
    int tx = threadIdx.x & 31, ty = threadIdx.x >> 5;
    int r0 = blockIdx.y * 32, c0 = blockIdx.x * 32;
#pragma unroll
    for (int i = 0; i < 32; i += 8)
        tile[ty + i][tx] = in[(long)(r0 + ty + i) * C + c0 + tx];
    __syncthreads();
#pragma unroll
    for (int i = 0; i < 32; i += 8)
        out[(long)(c0 + ty + i) * R + r0 + tx] = (bf16)tile[tx][ty + i];
}

// ---------------- layernorm fp32 in -> bf16 out ----------------
template<int DIM, int NT>
__global__ __launch_bounds__(NT) void ln_to_bf16(
    const float* __restrict__ in, const float* __restrict__ g,
    const float* __restrict__ bb, bf16* __restrict__ out)
{
    constexpr int NW = NT / 64;
    long row = blockIdx.x;
    const float4* x4 = (const float4*)(in + row * DIM);
    float4 v = x4[threadIdx.x];
    float s = v.x + v.y + v.z + v.w;
    float s2 = v.x*v.x + v.y*v.y + v.z*v.z + v.w*v.w;
#pragma unroll
    for (int o = 32; o; o >>= 1) { s += __shfl_xor(s, o); s2 += __shfl_xor(s2, o); }
    __shared__ float red[2][NW];
    int w = threadIdx.x >> 6;
    if ((threadIdx.x & 63) == 0) { red[0][w] = s; red[1][w] = s2; }
    __syncthreads();
    s = 0.f; s2 = 0.f;
#pragma unroll
    for (int i = 0; i < NW; ++i) { s += red[0][i]; s2 += red[1][i]; }
    float mean = s * (1.f / DIM);
    float rstd = rsqrtf(s2 * (1.f / DIM) - mean * mean + 1e-5f);
    int c = threadIdx.x * 4;
    float4 gg = *(const float4*)(g + c);
    float4 bv = *(const float4*)(bb + c);
    bf16x4 ov;
    ov[0] = (bf16)((v.x - mean) * rstd * gg.x + bv.x);
    ov[1] = (bf16)((v.y - mean) * rstd * gg.y + bv.y);
    ov[2] = (bf16)((v.z - mean) * rstd * gg.z + bv.z);
    ov[3] = (bf16)((v.w - mean) * rstd * gg.w + bv.w);
    *(bf16x4*)(out + row * DIM + c) = ov;
}

// ---------------- mask all-ones flags per (b, qtile64, ktile64) ----------------
__global__ __launch_bounds__(256) void mask_flags(
    const float* __restrict__ mask, unsigned char* __restrict__ flags)
{
    int blk = blockIdx.x;                  // b*256 + qt*16 + kt
    int b = blk >> 8, qt = (blk >> 4) & 15, kt = blk & 15;
    const float* src = mask + ((long)(b * 1024 + qt * 64 + (threadIdx.x >> 2))) * 1024
                     + kt * 64 + (threadIdx.x & 3) * 16;
    int ok = 1;
#pragma unroll
    for (int u = 0; u < 16; u += 4) {
        float4 v = *(const float4*)(src + u);
        ok &= (v.x == 1.f) & (v.y == 1.f) & (v.z == 1.f) & (v.w == 1.f);
    }
    ok = __syncthreads_and(ok);
    if (threadIdx.x == 0) flags[blk] = (unsigned char)ok;
}

// ---------------- adaln: silu(emb) @ emb_W + emb_b -> (B, 2048) fp32 ----------------
__global__ __launch_bounds__(256) void adaln_gemm(
    const float* __restrict__ emb, const float* __restrict__ W,
    const float* __restrict__ eb, float* __restrict__ emo)
{
    __shared__ float es[1024];
    int b = blockIdx.y;
    int c = blockIdx.x * 256 + threadIdx.x;
    for (int i = threadIdx.x; i < 1024; i += 256) {
        float e = emb[b * 1024 + i];
        es[i] = e / (1.f + expf(-e));
    }
    __syncthreads();
    float acc = 0.f;
#pragma unroll 8
    for (int k = 0; k < 1024; ++k) acc += es[k] * W[(long)k * 2048 + c];
    emo[b * 2048 + c] = acc + eb[c];
}

// ---------------- GEMM: A(MxK) bf16 row-major @ Bt(NxK) bf16 row-major + bias ----------------
// OUT_MODE 0: bf16 out;  OUT_MODE 1: fp32 out = resid + acc + bias
template<int OUT_MODE>
__global__ __launch_bounds__(256) void gemm_bt(
    const bf16* __restrict__ A, const bf16* __restrict__ Bt,
    const float* __restrict__ bias, const float* __restrict__ resid,
    void* __restrict__ outp, int M, int N, int K)
{
    __shared__ __align__(16) bf16 As[128 * 32];
    __shared__ __align__(16) bf16 Bs[128 * 32];
    const int t = threadIdx.x;
    const int wave = t >> 6, lane = t & 63;
    const int brow = blockIdx.y * 128, bcol = blockIdx.x * 128;
    const int wr = wave >> 1, wc = wave & 1;
    const int srow = t >> 2, sc8 = (t & 3) * 8;
    const bf16* a0 = A + (long)(brow + srow) * K + sc8;
    const bf16* a1 = A + (long)(brow + 64 + srow) * K + sc8;
    const bf16* b0 = Bt + (long)(bcol + srow) * K + sc8;
    const bf16* b1 = Bt + (long)(bcol + 64 + srow) * K + sc8;
    char* asb = (char*)As + wave * 1024;
    char* bsb = (char*)Bs + wave * 1024;
    const int fr = lane & 15, fc = (lane >> 4) * 8;
    f32x4 acc[4][4] = {};
    for (int k0 = 0; k0 < K; k0 += 32) {
        __syncthreads();
        __builtin_amdgcn_global_load_lds(AS1C(a0 + k0), AS3(asb), 16, 0, 0);
        __builtin_amdgcn_global_load_lds(AS1C(a1 + k0), AS3(asb + 4096), 16, 0, 0);
        __builtin_amdgcn_global_load_lds(AS1C(b0 + k0), AS3(bsb), 16, 0, 0);
        __builtin_amdgcn_global_load_lds(AS1C(b1 + k0), AS3(bsb + 4096), 16, 0, 0);
        __syncthreads();
        bf16x8 af[4], bfr[4];
#pragma unroll
        for (int m = 0; m < 4; ++m)
            af[m] = *(const bf16x8*)&As[(wr * 64 + m * 16 + fr) * 32 + fc];
#pragma unroll
        for (int n = 0; n < 4; ++n)
            bfr[n] = *(const bf16x8*)&Bs[(wc * 64 + n * 16 + fr) * 32 + fc];
#pragma unroll
        for (int m = 0; m < 4; ++m)
#pragma unroll
            for (int n = 0; n < 4; ++n)
                acc[m][n] = __builtin_amdgcn_mfma_f32_16x16x32_bf16(af[m], bfr[n], acc[m][n], 0, 0, 0);
    }
    const int er = (lane >> 4) * 4, ec = lane & 15;
    if constexpr (OUT_MODE == 0) {
        bf16* C = (bf16*)outp;
#pragma unroll
        for (int n = 0; n < 4; ++n) {
            int col = bcol + wc * 64 + n * 16 + ec;
            float bcv = bias[col];
#pragma unroll
            for (int m = 0; m < 4; ++m) {
                long rbase = (long)(brow + wr * 64 + m * 16 + er) * N + col;
#pragma unroll
                for (int j = 0; j < 4; ++j)
                    C[rbase + (long)j * N] = (bf16)(acc[m][n][j] + bcv);
            }
        }
    } else {
        float* C = (float*)outp;
#pragma unroll
        for (int n = 0; n < 4; ++n) {
            int col = bcol + wc * 64 + n * 16 + ec;
            float bcv = bias[col];
#pragma unroll
            for (int m = 0; m < 4; ++m) {
                long rbase = (long)(brow + wr * 64 + m * 16 + er) * N + col;
#pragma unroll
                for (int j = 0; j < 4; ++j) {
                    long idx = rbase + (long)j * N;
                    C[idx] = resid[idx] + acc[m][n][j] + bcv;
                }
            }
        }
    }
}

// ---------------- flash attention ----------------
// grid: (T/64, B*H); block 256 (4 waves, 16 q-rows each). KV tile = 64.
__global__ __launch_bounds__(256) void flash_attn(
    const bf16* __restrict__ Q, const bf16* __restrict__ Km, const bf16* __restrict__ Vm,
    const float* __restrict__ mask, const unsigned char* __restrict__ flags,
    bf16* __restrict__ Y)
{
    const int qt = blockIdx.x, bh = blockIdx.y;
    const int b = bh >> 4, h = bh & 15;
    const int t = threadIdx.x, wave = t >> 6, lane = t & 63;
    const int la = lane >> 4, lb = lane & 15;

    __shared__ __align__(16) bf16 Ks[64 * 64];      // XOR-swizzled chunk placement
    __shared__ __align__(16) bf16 Vt[64 * 72];      // [hd][key], padded stride 72
    __shared__ __align__(16) bf16 Ps[4][16 * 72];   // per-wave P tile [q][key]

    const int qrow = qt * 64 + wave * 16;
    bf16x8 qf[2];
    {
        const bf16* qp = Q + (long)(b * 1024 + qrow + lb) * 1024 + h * 64 + la * 8;
        qf[0] = *(const bf16x8*)qp;
        qf[1] = *(const bf16x8*)(qp + 32);
    }
    f32x4 o[4] = {};
    float mrow[4] = {-1e30f, -1e30f, -1e30f, -1e30f};
    float lrow[4] = {0.f, 0.f, 0.f, 0.f};

    const int krow = t >> 3, kc = t & 7;
    const bf16* Kbase = Km + (long)b * 1024 * 1024 + h * 64;
    const bf16* Vbase = Vm + (long)b * 1024 * 1024 + h * 64;
    const bf16* kg0 = Kbase + (long)krow * 1024 + ((kc ^ (krow & 7)) * 8);
    char* ksb = (char*)Ks + wave * 1024;
    const int vkey = t & 63, vhd0 = (t >> 6) * 16;
    const bf16* vg = Vbase + (long)vkey * 1024 + vhd0;

    const unsigned char* flagrow = flags + b * 256 + qt * 16;
    bf16* pw = &Ps[wave][0];
    const float* mbase = mask + (long)(b * 1024 + qrow + la * 4) * 1024 + lb;

    for (int kv = 0; kv < 16; ++kv) {
        const int key0 = kv * 64;
        __syncthreads();
        // K tile: global_load_lds, source pre-swizzled (chunk ^= row&7)
        __builtin_amdgcn_global_load_lds(AS1C(kg0 + (long)key0 * 1024), AS3(ksb), 16, 0, 0);
        __builtin_amdgcn_global_load_lds(AS1C(kg0 + (long)(key0 + 32) * 1024), AS3(ksb + 4096), 16, 0, 0);
        // V tile transposed into LDS
        {
            const bf16* vp = vg + (long)key0 * 1024;
            bf16x8 v0 = *(const bf16x8*)vp;
            bf16x8 v1 = *(const bf16x8*)(vp + 8);
#pragma unroll
            for (int j = 0; j < 8; ++j) Vt[(vhd0 + j) * 72 + vkey] = v0[j];
#pragma unroll
            for (int j = 0; j < 8; ++j) Vt[(vhd0 + 8 + j) * 72 + vkey] = v1[j];
        }
        __syncthreads();

        // S = (Q K^T) / 8 ; S fragment: row q = la*4+r, col key = n*16+lb
        float sc[4][4];
#pragma unroll
        for (int n = 0; n < 4; ++n) {
            const int row = n * 16 + lb;
            bf16x8 kf0 = *(const bf16x8*)&Ks[row * 64 + (((la)     ^ (lb & 7)) * 8)];
            bf16x8 kf1 = *(const bf16x8*)&Ks[row * 64 + (((la + 4) ^ (lb & 7)) * 8)];
            f32x4 acc = {};
            acc = __builtin_amdgcn_mfma_f32_16x16x32_bf16(qf[0], kf0, acc, 0, 0, 0);
            acc = __builtin_amdgcn_mfma_f32_16x16x32_bf16(qf[1], kf1, acc, 0, 0, 0);
#pragma unroll
            for (int r = 0; r < 4; ++r) sc[n][r] = acc[r] * 0.125f;
        }
        if (!flagrow[kv]) {
#pragma unroll
            for (int r = 0; r < 4; ++r)
#pragma unroll
                for (int n = 0; n < 4; ++n)
                    sc[n][r] += (1.f - mbase[(long)r * 1024 + key0 + n * 16]) * -100000.f;
        }
        // online softmax (reduce across 16 lanes holding the row's keys)
        float pv[4][4], al[4];
#pragma unroll
        for (int r = 0; r < 4; ++r) {
            float mx = fmaxf(fmaxf(sc[0][r], sc[1][r]), fmaxf(sc[2][r], sc[3][r]));
#pragma unroll
            for (int off = 1; off < 16; off <<= 1) mx = fmaxf(mx, __shfl_xor(mx, off));
            float mnew = fmaxf(mrow[r], mx);
            al[r] = exp2f((mrow[r] - mnew) * 1.44269504f);
            mrow[r] = mnew;
            float rs = 0.f;
#pragma unroll
            for (int n = 0; n < 4; ++n) {
                float p = exp2f((sc[n][r] - mnew) * 1.44269504f);
                pv[n][r] = p; rs += p;
            }
#pragma unroll
            for (int off = 1; off < 16; off <<= 1) rs += __shfl_xor(rs, off);
            lrow[r] = lrow[r] * al[r] + rs;
        }
#pragma unroll
        for (int n = 0; n < 4; ++n)
#pragma unroll
            for (int j = 0; j < 4; ++j) o[n][j] *= al[j];
        // P -> LDS (per-wave, no barrier needed: same-wave DS ops are in-order)
#pragma unroll
        for (int r = 0; r < 4; ++r)
#pragma unroll
            for (int n = 0; n < 4; ++n)
                pw[(la * 4 + r) * 72 + n * 16 + lb] = (bf16)pv[n][r];
        asm volatile("s_waitcnt lgkmcnt(0)" ::: "memory");
        // O += P @ V
#pragma unroll
        for (int kb = 0; kb < 2; ++kb) {
            bf16x8 pf = *(const bf16x8*)&pw[lb * 72 + kb * 32 + la * 8];
#pragma unroll
            for (int n = 0; n < 4; ++n) {
                bf16x8 vf = *(const bf16x8*)&Vt[(n * 16 + lb) * 72 + kb * 32 + la * 8];
                o[n] = __builtin_amdgcn_mfma_f32_16x16x32_bf16(pf, vf, o[n], 0, 0, 0);
            }
        }
    }
    float inv[4];
#pragma unroll
    for (int r = 0; r < 4; ++r) inv[r] = 1.f / lrow[r];
    bf16* yp = Y + (long)(b * 1024 + qrow + la * 4) * 1024 + h * 64 + lb;
#pragma unroll
    for (int n = 0; n < 4; ++n)
#pragma unroll
        for (int j = 0; j < 4; ++j)
            yp[(long)j * 1024 + n * 16] = (bf16)(o[n][j] * inv[j]);
}

// ---------------- LN(y)*(1+scale)+shift -> silu -> bf16 ----------------
__global__ __launch_bounds__(256) void ln_mod_silu(
    const bf16* __restrict__ Yin, const float* __restrict__ g, const float* __restrict__ bb,
    const float* __restrict__ emo, bf16* __restrict__ act)
{
    long row = blockIdx.x;
    int b = (int)(row >> 10);
    const bf16* y = Yin + row * 1024;
    int c = threadIdx.x * 4;
    bf16x4 yv = *(const bf16x4*)(y + c);
    float v0 = (float)yv[0], v1 = (float)yv[1], v2 = (float)yv[2], v3 = (float)yv[3];
    float s = v0 + v1 + v2 + v3, s2 = v0*v0 + v1*v1 + v2*v2 + v3*v3;
#pragma unroll
    for (int o = 32; o; o >>= 1) { s += __shfl_xor(s, o); s2 += __shfl_xor(s2, o); }
    __shared__ float red[2][4];
    int w = threadIdx.x >> 6;
    if ((threadIdx.x & 63) == 0) { red[0][w] = s; red[1][w] = s2; }
    __syncthreads();
    s = red[0][0] + red[0][1] + red[0][2] + red[0][3];
    s2 = red[1][0] + red[1][1] + red[1][2] + red[1][3];
    float mean = s * (1.f / 1024.f);
    float rstd = rsqrtf(s2 * (1.f / 1024.f) - mean * mean + 1e-5f);
    float4 gg = *(const float4*)(g + c);
    float4 bv = *(const float4*)(bb + c);
    float4 scv = *(const float4*)(emo + b * 2048 + c);
    float4 shv = *(const float4*)(emo + b * 2048 + 1024 + c);
    float hv[4];
    hv[0] = ((v0 - mean) * rstd * gg.x + bv.x) * (1.f + scv.x) + shv.x;
    hv[1] = ((v1 - mean) * rstd * gg.y + bv.y) * (1.f + scv.y) + shv.y;
    hv[2] = ((v2 - mean) * rstd * gg.z + bv.z) * (1.f + scv.z) + shv.z;
    hv[3] = ((v3 - mean) * rstd * gg.w + bv.w) * (1.f + scv.w) + shv.w;
    bf16x4 ov;
#pragma unroll
    for (int j = 0; j < 4; ++j) ov[j] = (bf16)(hv[j] / (1.f + expf(-hv[j])));
    *(bf16x4*)(act + row * 1024 + c) = ov;
}

extern "C" void kernel_launch(void* const* d_in, const int* in_sizes, int n_in,
                              void* d_out, int out_size, void* d_ws, size_t ws_size,
                              hipStream_t stream)
{
    const float* x     = (const float*)d_in[0];
    const float* xf    = (const float*)d_in[1];
    const float* emb   = (const float*)d_in[2];
    const float* mask  = (const float*)d_in[3];
    const float* ln_g  = (const float*)d_in[4];
    const float* ln_b  = (const float*)d_in[5];
    const float* aln_g = (const float*)d_in[6];
    const float* aln_b = (const float*)d_in[7];
    const float* n2_g  = (const float*)d_in[8];
    const float* n2_b  = (const float*)d_in[9];
    const float* Wq    = (const float*)d_in[10];
    const float* bq    = (const float*)d_in[11];
    const float* Wk    = (const float*)d_in[12];
    const float* bk    = (const float*)d_in[13];
    const float* Wv    = (const float*)d_in[14];
    const float* bv    = (const float*)d_in[15];
    const float* emb_W = (const float*)d_in[16];
    const float* emb_b = (const float*)d_in[17];
    const float* out_W = (const float*)d_in[18];
    const float* out_b = (const float*)d_in[19];
    float* out = (float*)d_out;

    char* w = (char*)d_ws;
    bf16* xn   = (bf16*)w; w += (size_t)4096 * 1024 * 2;   // 8 MB
    bf16* xfn  = (bf16*)w; w += (size_t)4096 * 512 * 2;    // 4 MB
    bf16* WqT  = (bf16*)w; w += (size_t)1024 * 1024 * 2;   // 2 MB
    bf16* WkT  = (bf16*)w; w += (size_t)1024 * 512 * 2;    // 1 MB
    bf16* WvT  = (bf16*)w; w += (size_t)1024 * 512 * 2;    // 1 MB
    bf16* WoT  = (bf16*)w; w += (size_t)1024 * 1024 * 2;   // 2 MB
    bf16* qb   = (bf16*)w; w += (size_t)4096 * 1024 * 2;   // 8 MB
    bf16* kb_  = (bf16*)w; w += (size_t)4096 * 1024 * 2;   // 8 MB
    bf16* vb_  = (bf16*)w; w += (size_t)4096 * 1024 * 2;   // 8 MB
    bf16* yb   = (bf16*)w; w += (size_t)4096 * 1024 * 2;   // 8 MB
    bf16* actb = (bf16*)w; w += (size_t)4096 * 1024 * 2;   // 8 MB
    float* emo = (float*)w; w += (size_t)4 * 2048 * 4;     // 32 KB
    unsigned char* flg = (unsigned char*)w;                // 1 KB

    // weight transposes (fp32 -> bf16, (K,N) -> (N,K))
    transpose_cast<<<dim3(32, 32), 256, 0, stream>>>(Wq,    WqT, 1024, 1024);
    transpose_cast<<<dim3(32, 16), 256, 0, stream>>>(Wk,    WkT,  512, 1024);
    transpose_cast<<<dim3(32, 16), 256, 0, stream>>>(Wv,    WvT,  512, 1024);
    transpose_cast<<<dim3(32, 32), 256, 0, stream>>>(out_W, WoT, 1024, 1024);

    ln_to_bf16<1024, 256><<<4096, 256, 0, stream>>>(x,  ln_g,  ln_b,  xn);
    ln_to_bf16<512, 128><<<4096, 128, 0, stream>>>(xf, aln_g, aln_b, xfn);
    mask_flags<<<1024, 256, 0, stream>>>(mask, flg);
    adaln_gemm<<<dim3(8, 4), 256, 0, stream>>>(emb, emb_W, emb_b, emo);

    gemm_bt<0><<<dim3(8, 32), 256, 0, stream>>>(xn,  WqT, bq, nullptr, qb,  4096, 1024, 1024);
    gemm_bt<0><<<dim3(8, 32), 256, 0, stream>>>(xfn, WkT, bk, nullptr, kb_, 4096, 1024, 512);
    gemm_bt<0><<<dim3(8, 32), 256, 0, stream>>>(xfn, WvT, bv, nullptr, vb_, 4096, 1024, 512);

    flash_attn<<<dim3(16, 64), 256, 0, stream>>>(qb, kb_, vb_, mask, flg, yb);

    ln_mod_silu<<<4096, 256, 0, stream>>>(yb, n2_g, n2_b, emo, actb);
    gemm_bt<1><<<dim3(8, 32), 256, 0, stream>>>(actb, WoT, out_b, x, out, 4096, 1024, 1024);
}

// Round 7
// 300.005 us; speedup vs baseline: 1.1964x; 1.1964x over previous
//
#include <hip/hip_runtime.h>

typedef __bf16 bf16;
typedef __bf16 bf16x4 __attribute__((ext_vector_type(4)));
typedef __bf16 bf16x8 __attribute__((ext_vector_type(8)));
typedef float f32x4 __attribute__((ext_vector_type(4)));

#define AS1C(p) ((const __attribute__((address_space(1))) void*)(p))
#define AS3(p)  ((__attribute__((address_space(3))) void*)(p))

// ---------------- transpose fp32 (R x C) -> bf16 (C x R) ----------------
__global__ __launch_bounds__(256) void transpose_cast(
    const float* __restrict__ in, bf16* __restrict__ out, int R, int C)
{
    __shared__ float tile[32][33];
    int tx = threadIdx.x & 31, ty = threadIdx.x >> 5;
    int r0 = blockIdx.y * 32, c0 = blockIdx.x * 32;
#pragma unroll
    for (int i = 0; i < 32; i += 8)
        tile[ty + i][tx] = in[(long)(r0 + ty + i) * C + c0 + tx];
    __syncthreads();
#pragma unroll
    for (int i = 0; i < 32; i += 8)
        out[(long)(c0 + ty + i) * R + r0 + tx] = (bf16)tile[tx][ty + i];
}

__global__ __launch_bounds__(256) void concat_bias(
    const float* __restrict__ b0, const float* __restrict__ b1, float* __restrict__ o)
{
    int c = blockIdx.x * 256 + threadIdx.x;
    o[c] = (c < 1024) ? b0[c] : b1[c - 1024];
}

// ---------------- layernorm fp32 in -> bf16 out ----------------
template<int DIM, int NT>
__global__ __launch_bounds__(NT) void ln_to_bf16(
    const float* __restrict__ in, const float* __restrict__ g,
    const float* __restrict__ bb, bf16* __restrict__ out)
{
    constexpr int NW = NT / 64;
    long row = blockIdx.x;
    const float4* x4 = (const float4*)(in + row * DIM);
    float4 v = x4[threadIdx.x];
    float s = v.x + v.y + v.z + v.w;
    float s2 = v.x*v.x + v.y*v.y + v.z*v.z + v.w*v.w;
#pragma unroll
    for (int o = 32; o; o >>= 1) { s += __shfl_xor(s, o); s2 += __shfl_xor(s2, o); }
    __shared__ float red[2][NW];
    int w = threadIdx.x >> 6;
    if ((threadIdx.x & 63) == 0) { red[0][w] = s; red[1][w] = s2; }
    __syncthreads();
    s = 0.f; s2 = 0.f;
#pragma unroll
    for (int i = 0; i < NW; ++i) { s += red[0][i]; s2 += red[1][i]; }
    float mean = s * (1.f / DIM);
    float rstd = rsqrtf(s2 * (1.f / DIM) - mean * mean + 1e-5f);
    int c = threadIdx.x * 4;
    float4 gg = *(const float4*)(g + c);
    float4 bv = *(const float4*)(bb + c);
    bf16x4 ov;
    ov[0] = (bf16)((v.x - mean) * rstd * gg.x + bv.x);
    ov[1] = (bf16)((v.y - mean) * rstd * gg.y + bv.y);
    ov[2] = (bf16)((v.z - mean) * rstd * gg.z + bv.z);
    ov[3] = (bf16)((v.w - mean) * rstd * gg.w + bv.w);
    *(bf16x4*)(out + row * DIM + c) = ov;
}

// ---------------- mask all-ones flags per (b, qtile64, ktile64) ----------------
__global__ __launch_bounds__(256) void mask_flags(
    const float* __restrict__ mask, unsigned char* __restrict__ flags)
{
    int blk = blockIdx.x;                  // b*256 + qt*16 + kt
    int b = blk >> 8, qt = (blk >> 4) & 15, kt = blk & 15;
    const float* src = mask + ((long)(b * 1024 + qt * 64 + (threadIdx.x >> 2))) * 1024
                     + kt * 64 + (threadIdx.x & 3) * 16;
    int ok = 1;
#pragma unroll
    for (int u = 0; u < 16; u += 4) {
        float4 v = *(const float4*)(src + u);
        ok &= (v.x == 1.f) & (v.y == 1.f) & (v.z == 1.f) & (v.w == 1.f);
    }
    ok = __syncthreads_and(ok);
    if (threadIdx.x == 0) flags[blk] = (unsigned char)ok;
}

// ---------------- adaln: silu(emb) @ emb_W + emb_b -> (B, 2048) fp32 ----------------
// grid (32, B); 64 cols x 4 k-groups per block
__global__ __launch_bounds__(256) void adaln_gemm2(
    const float* __restrict__ emb, const float* __restrict__ W,
    const float* __restrict__ eb, float* __restrict__ emo)
{
    __shared__ float es[1024];
    __shared__ float part[4][64];
    int b = blockIdx.y, t = threadIdx.x;
    int kg = t >> 6, c = t & 63;
    int col = blockIdx.x * 64 + c;
    for (int i = t; i < 1024; i += 256) {
        float e = emb[b * 1024 + i];
        es[i] = e / (1.f + expf(-e));
    }
    __syncthreads();
    float acc = 0.f;
    const float* wp = W + (long)(kg * 256) * 2048 + col;
    const float* ep = es + kg * 256;
#pragma unroll 4
    for (int k = 0; k < 256; ++k) acc += ep[k] * wp[(long)k * 2048];
    part[kg][c] = acc;
    __syncthreads();
    if (t < 64) {
        int col0 = blockIdx.x * 64 + t;
        emo[b * 2048 + col0] = part[0][t] + part[1][t] + part[2][t] + part[3][t] + eb[col0];
    }
}

// ---------------- GEMM 64x128 tile: A(MxK) bf16 RM @ Bt(NxK) bf16 RM + bias ----------------
// OUT_MODE 0: bf16 out;  OUT_MODE 1: fp32 out = resid + acc + bias
template<int OUT_MODE>
__global__ __launch_bounds__(256) void gemm64(
    const bf16* __restrict__ A, const bf16* __restrict__ Bt,
    const float* __restrict__ bias, const float* __restrict__ resid,
    void* __restrict__ outp, int M, int N, int K)
{
    __shared__ __align__(16) bf16 As[64 * 32];    // 4 KB
    __shared__ __align__(16) bf16 Bs[128 * 32];   // 8 KB
    const int t = threadIdx.x;
    const int wave = t >> 6, lane = t & 63;
    const int brow = blockIdx.y * 64, bcol = blockIdx.x * 128;
    const int wr = wave & 1, wc = wave >> 1;
    const int sr = lane >> 2, sc8 = (lane & 3) * 8;
    const bf16* aS  = A  + (long)(brow + wave * 16 + sr) * K + sc8;
    const bf16* bS0 = Bt + (long)(bcol + wave * 32 + sr) * K + sc8;
    const bf16* bS1 = bS0 + (long)16 * K;
    char* asw = (char*)As + wave * 1024;
    char* bsw = (char*)Bs + wave * 2048;
    const int fr = lane & 15, fc = (lane >> 4) * 8;
    f32x4 acc[2][4] = {};
    for (int k0 = 0; k0 < K; k0 += 32) {
        __syncthreads();
        __builtin_amdgcn_global_load_lds(AS1C(aS + k0),  AS3(asw), 16, 0, 0);
        __builtin_amdgcn_global_load_lds(AS1C(bS0 + k0), AS3(bsw), 16, 0, 0);
        __builtin_amdgcn_global_load_lds(AS1C(bS1 + k0), AS3(bsw + 1024), 16, 0, 0);
        __syncthreads();
        bf16x8 af[2], bfr[4];
#pragma unroll
        for (int m = 0; m < 2; ++m)
            af[m] = *(const bf16x8*)&As[(wr * 32 + m * 16 + fr) * 32 + fc];
#pragma unroll
        for (int n = 0; n < 4; ++n)
            bfr[n] = *(const bf16x8*)&Bs[(wc * 64 + n * 16 + fr) * 32 + fc];
        __builtin_amdgcn_s_setprio(1);
#pragma unroll
        for (int m = 0; m < 2; ++m)
#pragma unroll
            for (int n = 0; n < 4; ++n)
                acc[m][n] = __builtin_amdgcn_mfma_f32_16x16x32_bf16(af[m], bfr[n], acc[m][n], 0, 0, 0);
        __builtin_amdgcn_s_setprio(0);
    }
    const int er = (lane >> 4) * 4, ec = lane & 15;
    if constexpr (OUT_MODE == 0) {
        bf16* C = (bf16*)outp;
#pragma unroll
        for (int n = 0; n < 4; ++n) {
            int col = bcol + wc * 64 + n * 16 + ec;
            float bcv = bias[col];
#pragma unroll
            for (int m = 0; m < 2; ++m) {
                long rbase = (long)(brow + wr * 32 + m * 16 + er) * N + col;
#pragma unroll
                for (int j = 0; j < 4; ++j)
                    C[rbase + (long)j * N] = (bf16)(acc[m][n][j] + bcv);
            }
        }
    } else {
        float* C = (float*)outp;
#pragma unroll
        for (int n = 0; n < 4; ++n) {
            int col = bcol + wc * 64 + n * 16 + ec;
            float bcv = bias[col];
#pragma unroll
            for (int m = 0; m < 2; ++m) {
                long rbase = (long)(brow + wr * 32 + m * 16 + er) * N + col;
#pragma unroll
                for (int j = 0; j < 4; ++j) {
                    long idx = rbase + (long)j * N;
                    C[idx] = resid[idx] + acc[m][n][j] + bcv;
                }
            }
        }
    }
}

// ---------------- V transpose into swizzle-baked tiles ----------------
// out layout: vt[bh][kvt][d(64)][c(8)][j(8)] with tile[d][c] = V[key=8*(c^phi(d))+j][d]
// phi(d) = (d&3) | (((d>>3)&1)<<2)
__global__ __launch_bounds__(256) void vtrans(
    const bf16* __restrict__ kvb, bf16* __restrict__ vt)
{
    __shared__ bf16 tile[64 * 72];   // [key][d], stride 72 (144B, 16B-aligned)
    int kvt = blockIdx.x, bh = blockIdx.y;
    int b = bh >> 4, h = bh & 15;
    int t = threadIdx.x;
    {
        int key = t >> 2, d0 = (t & 3) * 16;
        const bf16* src = kvb + (long)(b * 1024 + kvt * 64 + key) * 2048 + 1024 + h * 64 + d0;
        bf16x8 v0 = *(const bf16x8*)src;
        bf16x8 v1 = *(const bf16x8*)(src + 8);
        *(bf16x8*)&tile[key * 72 + d0] = v0;
        *(bf16x8*)&tile[key * 72 + d0 + 8] = v1;
    }
    __syncthreads();
    bf16* vtile = vt + ((long)(bh * 16 + kvt)) * 4096;
    int d = t >> 2;
    int phi = (d & 3) | (((d >> 3) & 1) << 2);
#pragma unroll
    for (int half = 0; half < 2; ++half) {
        int c = (t & 3) + half * 4;
        int key8 = 8 * (c ^ phi);
        bf16x8 w;
#pragma unroll
        for (int j = 0; j < 8; ++j) w[j] = tile[(key8 + j) * 72 + d];
        *(bf16x8*)&vtile[d * 64 + c * 8] = w;
    }
}

// ---------------- flash attention (swapped QK^T, zero-shuffle P) ----------------
// grid 1024 (flat), block 256 (4 waves x 16 q rows). KV tile = 64.
__global__ __launch_bounds__(256, 4) void flash2(
    const bf16* __restrict__ Q, const bf16* __restrict__ KV, const bf16* __restrict__ VT,
    const float* __restrict__ mask, const unsigned char* __restrict__ flags,
    bf16* __restrict__ Y)
{
    const int f = blockIdx.x;
    const int bh = f & 63;                 // 8 distinct bh per XCD -> 2MB KV fits L2
    const int qt = f >> 6;
    const int b = bh >> 4, h = bh & 15;
    const int t = threadIdx.x, wave = t >> 6, lane = t & 63;
    const int la = lane >> 4, lb = lane & 15;

    __shared__ __align__(16) bf16 Ks[64 * 64];   // [key][hd], chunk^=phiK(key)
    __shared__ __align__(16) bf16 Vs[64 * 64];   // [d][key],  chunk^=phiV(d)

    const int qrow = qt * 64 + wave * 16;
    bf16x8 qf0, qf1;
    {
        const bf16* qp = Q + (long)(b * 1024 + qrow + lb) * 1024 + h * 64 + la * 8;
        qf0 = *(const bf16x8*)qp;
        qf1 = *(const bf16x8*)(qp + 32);
    }
    f32x4 o[4] = {};
    float m_run = -3e38f, l_run = 0.f;
    const float CL = 0.125f * 1.44269504f;   // fold 1/sqrt(64) and log2(e)

    // staging addresses (linear LDS dest; source pre-swizzled)
    const int srow = lane >> 3, sc = lane & 7;
    const int phiS = (srow & 3) | ((wave & 1) << 2);
    const bf16* kS = KV + (long)(b * 1024 + wave * 8 + srow) * 2048 + h * 64 + ((sc ^ phiS) * 8);
    const bf16* vS = VT + (long)(bh * 16) * 4096 + wave * 512 + lane * 8;
    char* kDst = (char*)Ks + wave * 1024;
    char* vDst = (char*)Vs + wave * 1024;

    // fragment read bases
    const int phiK = (lb & 3) | (((lb >> 2) & 1) << 2);
    const int phiV = (lb & 3) | (((lb >> 3) & 1) << 2);
    const int rbase = (lb >> 2) * 8 + (lb & 3);
    const bf16* kf0 = &Ks[rbase * 64 + ((la ^ phiK) * 8)];
    const bf16* kf1 = &Ks[rbase * 64 + (((4 + la) ^ phiK) * 8)];
    const bf16* vf0 = &Vs[lb * 64 + ((la ^ phiV) * 8)];
    const bf16* vf1 = &Vs[lb * 64 + (((4 + la) ^ phiV) * 8)];
    const int rowoff[4] = {0, 2048, 256, 2304};   // rows {0,32,4,36} * 64 elems

    const unsigned char* flagrow = flags + b * 256 + qt * 16;
    const float* mrow_p = mask + (long)(b * 1024 + qrow + lb) * 1024;

    for (int kv = 0; kv < 16; ++kv) {
        const int key0 = kv * 64;
        __syncthreads();
        __builtin_amdgcn_global_load_lds(AS1C(kS + (long)key0 * 2048),        AS3(kDst),        16, 0, 0);
        __builtin_amdgcn_global_load_lds(AS1C(kS + (long)(key0 + 32) * 2048), AS3(kDst + 4096), 16, 0, 0);
        __builtin_amdgcn_global_load_lds(AS1C(vS + kv * 4096),                AS3(vDst),        16, 0, 0);
        __builtin_amdgcn_global_load_lds(AS1C(vS + kv * 4096 + 2048),         AS3(vDst + 4096), 16, 0, 0);
        __syncthreads();

        // S^T = K Q^T : lane holds S[key=(n&1)*32+la*8+(n>>1)*4+r][q=lb]
        f32x4 s[4] = {};
        __builtin_amdgcn_s_setprio(1);
#pragma unroll
        for (int n = 0; n < 4; ++n) {
            s[n] = __builtin_amdgcn_mfma_f32_16x16x32_bf16(*(const bf16x8*)(kf0 + rowoff[n]), qf0, s[n], 0, 0, 0);
            s[n] = __builtin_amdgcn_mfma_f32_16x16x32_bf16(*(const bf16x8*)(kf1 + rowoff[n]), qf1, s[n], 0, 0, 0);
        }
        __builtin_amdgcn_s_setprio(0);

        if (!flagrow[kv]) {   // mask in raw-score units (x8)
#pragma unroll
            for (int n = 0; n < 4; ++n)
#pragma unroll
                for (int r = 0; r < 4; ++r) {
                    int key = (n & 1) * 32 + la * 8 + (n >> 1) * 4 + r;
                    s[n][r] += (1.f - mrow_p[key0 + key]) * -800000.f;
                }
        }

        // online softmax: row q=lb, reduce 16 local + across la (lanes ^16, ^32)
        float t0 = fmaxf(fmaxf(s[0][0], s[0][1]), fmaxf(s[0][2], s[0][3]));
        float t1 = fmaxf(fmaxf(s[1][0], s[1][1]), fmaxf(s[1][2], s[1][3]));
        float t2 = fmaxf(fmaxf(s[2][0], s[2][1]), fmaxf(s[2][2], s[2][3]));
        float t3 = fmaxf(fmaxf(s[3][0], s[3][1]), fmaxf(s[3][2], s[3][3]));
        float tmax = fmaxf(fmaxf(t0, t1), fmaxf(t2, t3));
        tmax = fmaxf(tmax, __shfl_xor(tmax, 16));
        tmax = fmaxf(tmax, __shfl_xor(tmax, 32));
        float mnew = fmaxf(m_run, tmax);
        float al = exp2f((m_run - mnew) * CL);
        m_run = mnew;
        float p[4][4];
        float rsum = 0.f;
#pragma unroll
        for (int n = 0; n < 4; ++n)
#pragma unroll
            for (int r = 0; r < 4; ++r) {
                p[n][r] = exp2f((s[n][r] - mnew) * CL);
                rsum += p[n][r];
            }
        rsum += __shfl_xor(rsum, 16);
        rsum += __shfl_xor(rsum, 32);
        l_run = l_run * al + rsum;
#pragma unroll
        for (int d = 0; d < 4; ++d) o[d] *= al;

        // P -> B-frags (register packing only; zero cross-lane movement)
        bf16x8 pb0, pb1;
#pragma unroll
        for (int j = 0; j < 4; ++j) {
            pb0[j] = (bf16)p[0][j]; pb0[j + 4] = (bf16)p[2][j];
            pb1[j] = (bf16)p[1][j]; pb1[j + 4] = (bf16)p[3][j];
        }

        // O^T += V^T P : A=Vs rows d, B=P^T
        __builtin_amdgcn_s_setprio(1);
#pragma unroll
        for (int d = 0; d < 4; ++d) {
            o[d] = __builtin_amdgcn_mfma_f32_16x16x32_bf16(*(const bf16x8*)(vf0 + d * 1024), pb0, o[d], 0, 0, 0);
            o[d] = __builtin_amdgcn_mfma_f32_16x16x32_bf16(*(const bf16x8*)(vf1 + d * 1024), pb1, o[d], 0, 0, 0);
        }
        __builtin_amdgcn_s_setprio(0);
    }

    float inv = 1.f / l_run;
    bf16* yp = Y + (long)(b * 1024 + qrow + lb) * 1024 + h * 64 + la * 4;
#pragma unroll
    for (int d = 0; d < 4; ++d) {
        bf16x4 yv;
#pragma unroll
        for (int j = 0; j < 4; ++j) yv[j] = (bf16)(o[d][j] * inv);
        *(bf16x4*)(yp + d * 16) = yv;
    }
}

// ---------------- LN(y)*(1+scale)+shift -> silu -> bf16 ----------------
__global__ __launch_bounds__(256) void ln_mod_silu(
    const bf16* __restrict__ Yin, const float* __restrict__ g, const float* __restrict__ bb,
    const float* __restrict__ emo, bf16* __restrict__ act)
{
    long row = blockIdx.x;
    int b = (int)(row >> 10);
    const bf16* y = Yin + row * 1024;
    int c = threadIdx.x * 4;
    bf16x4 yv = *(const bf16x4*)(y + c);
    float v0 = (float)yv[0], v1 = (float)yv[1], v2 = (float)yv[2], v3 = (float)yv[3];
    float s = v0 + v1 + v2 + v3, s2 = v0*v0 + v1*v1 + v2*v2 + v3*v3;
#pragma unroll
    for (int o = 32; o; o >>= 1) { s += __shfl_xor(s, o); s2 += __shfl_xor(s2, o); }
    __shared__ float red[2][4];
    int w = threadIdx.x >> 6;
    if ((threadIdx.x & 63) == 0) { red[0][w] = s; red[1][w] = s2; }
    __syncthreads();
    s = red[0][0] + red[0][1] + red[0][2] + red[0][3];
    s2 = red[1][0] + red[1][1] + red[1][2] + red[1][3];
    float mean = s * (1.f / 1024.f);
    float rstd = rsqrtf(s2 * (1.f / 1024.f) - mean * mean + 1e-5f);
    float4 gg = *(const float4*)(g + c);
    float4 bv = *(const float4*)(bb + c);
    float4 scv = *(const float4*)(emo + b * 2048 + c);
    float4 shv = *(const float4*)(emo + b * 2048 + 1024 + c);
    float hv[4];
    hv[0] = ((v0 - mean) * rstd * gg.x + bv.x) * (1.f + scv.x) + shv.x;
    hv[1] = ((v1 - mean) * rstd * gg.y + bv.y) * (1.f + scv.y) + shv.y;
    hv[2] = ((v2 - mean) * rstd * gg.z + bv.z) * (1.f + scv.z) + shv.z;
    hv[3] = ((v3 - mean) * rstd * gg.w + bv.w) * (1.f + scv.w) + shv.w;
    bf16x4 ov;
#pragma unroll
    for (int j = 0; j < 4; ++j) ov[j] = (bf16)(hv[j] / (1.f + expf(-hv[j])));
    *(bf16x4*)(act + row * 1024 + c) = ov;
}

extern "C" void kernel_launch(void* const* d_in, const int* in_sizes, int n_in,
                              void* d_out, int out_size, void* d_ws, size_t ws_size,
                              hipStream_t stream)
{
    const float* x     = (const float*)d_in[0];
    const float* xf    = (const float*)d_in[1];
    const float* emb   = (const float*)d_in[2];
    const float* mask  = (const float*)d_in[3];
    const float* ln_g  = (const float*)d_in[4];
    const float* ln_b  = (const float*)d_in[5];
    const float* aln_g = (const float*)d_in[6];
    const float* aln_b = (const float*)d_in[7];
    const float* n2_g  = (const float*)d_in[8];
    const float* n2_b  = (const float*)d_in[9];
    const float* Wq    = (const float*)d_in[10];
    const float* bq    = (const float*)d_in[11];
    const float* Wk    = (const float*)d_in[12];
    const float* bk    = (const float*)d_in[13];
    const float* Wv    = (const float*)d_in[14];
    const float* bv    = (const float*)d_in[15];
    const float* emb_W = (const float*)d_in[16];
    const float* emb_b = (const float*)d_in[17];
    const float* out_W = (const float*)d_in[18];
    const float* out_b = (const float*)d_in[19];
    float* out = (float*)d_out;

    char* w = (char*)d_ws;
    bf16* xn   = (bf16*)w; w += (size_t)4096 * 1024 * 2;   // 8 MB (reused: vt, then actb)
    bf16* xfn  = (bf16*)w; w += (size_t)4096 * 512 * 2;    // 4 MB
    bf16* WqT  = (bf16*)w; w += (size_t)1024 * 1024 * 2;   // 2 MB
    bf16* WkvT = (bf16*)w; w += (size_t)2048 * 512 * 2;    // 2 MB
    bf16* WoT  = (bf16*)w; w += (size_t)1024 * 1024 * 2;   // 2 MB
    bf16* qb   = (bf16*)w; w += (size_t)4096 * 1024 * 2;   // 8 MB
    bf16* kvb  = (bf16*)w; w += (size_t)4096 * 2048 * 2;   // 16 MB
    bf16* yb   = (bf16*)w; w += (size_t)4096 * 1024 * 2;   // 8 MB
    float* bkv = (float*)w; w += (size_t)2048 * 4;         // 8 KB
    float* emo = (float*)w; w += (size_t)4 * 2048 * 4;     // 32 KB
    unsigned char* flg = (unsigned char*)w;                // 1 KB
    // lifetimes (stream-ordered, no overlap): xn -> Qgemm; vt -> flash; actb -> out-gemm
    bf16* vt   = xn;   // 64*16*4096 elems = 8 MB, written by vtrans AFTER Q-gemm reads xn
    bf16* actb = xn;   // written by ln_mod_silu AFTER flash reads vt

    transpose_cast<<<dim3(32, 32), 256, 0, stream>>>(Wq,    WqT, 1024, 1024);
    transpose_cast<<<dim3(32, 16), 256, 0, stream>>>(Wk,    WkvT, 512, 1024);
    transpose_cast<<<dim3(32, 16), 256, 0, stream>>>(Wv,    WkvT + (size_t)1024 * 512, 512, 1024);
    transpose_cast<<<dim3(32, 32), 256, 0, stream>>>(out_W, WoT, 1024, 1024);
    concat_bias<<<8, 256, 0, stream>>>(bk, bv, bkv);

    ln_to_bf16<1024, 256><<<4096, 256, 0, stream>>>(x,  ln_g,  ln_b,  xn);
    ln_to_bf16<512, 128><<<4096, 128, 0, stream>>>(xf, aln_g, aln_b, xfn);
    mask_flags<<<1024, 256, 0, stream>>>(mask, flg);
    adaln_gemm2<<<dim3(32, 4), 256, 0, stream>>>(emb, emb_W, emb_b, emo);

    gemm64<0><<<dim3(8, 64),  256, 0, stream>>>(xn,  WqT,  bq,  nullptr, qb,  4096, 1024, 1024);
    gemm64<0><<<dim3(16, 64), 256, 0, stream>>>(xfn, WkvT, bkv, nullptr, kvb, 4096, 2048, 512);
    vtrans<<<dim3(16, 64), 256, 0, stream>>>(kvb, vt);

    flash2<<<1024, 256, 0, stream>>>(qb, kvb, vt, mask, flg, yb);

    ln_mod_silu<<<4096, 256, 0, stream>>>(yb, n2_g, n2_b, emo, actb);
    gemm64<1><<<dim3(8, 64), 256, 0, stream>>>(actb, WoT, out_b, x, out, 4096, 1024, 1024);
}

// Round 10
// 261.413 us; speedup vs baseline: 1.3730x; 1.1476x over previous
//
#include <hip/hip_runtime.h>

typedef __bf16 bf16;
typedef __bf16 bf16x2 __attribute__((ext_vector_type(2)));
typedef __bf16 bf16x4 __attribute__((ext_vector_type(4)));
typedef __bf16 bf16x8 __attribute__((ext_vector_type(8)));
typedef float f32x4 __attribute__((ext_vector_type(4)));

#define AS1C(p) ((const __attribute__((address_space(1))) void*)(p))
#define AS3(p)  ((__attribute__((address_space(3))) void*)(p))

// ---------------- fused weight prep: 4 transposes (fp32 RxC -> bf16 CxR) + bias concat ----------------
__global__ __launch_bounds__(256) void prep(
    const float* __restrict__ Wq, const float* __restrict__ Wk,
    const float* __restrict__ Wv, const float* __restrict__ Wo,
    const float* __restrict__ bk, const float* __restrict__ bv,
    bf16* __restrict__ WqT, bf16* __restrict__ WkvT, bf16* __restrict__ WoT,
    float* __restrict__ bkv)
{
    int blk = blockIdx.x;
    if (blk >= 3072) {                       // 8 blocks: concat bias
        int c = (blk - 3072) * 256 + threadIdx.x;
        bkv[c] = (c < 1024) ? bk[c] : bv[c - 1024];
        return;
    }
    const float* in; bf16* out; int R, C, bx, by;
    if (blk < 1024)      { in = Wq; out = WqT; R = 1024; C = 1024; bx = blk & 31; by = blk >> 5; }
    else if (blk < 1536) { int g = blk - 1024; in = Wk; out = WkvT; R = 512; C = 1024; bx = g & 31; by = g >> 5; }
    else if (blk < 2048) { int g = blk - 1536; in = Wv; out = WkvT + (size_t)1024 * 512; R = 512; C = 1024; bx = g & 31; by = g >> 5; }
    else                 { int g = blk - 2048; in = Wo; out = WoT; R = 1024; C = 1024; bx = g & 31; by = g >> 5; }
    __shared__ float tile[32][33];
    int tx = threadIdx.x & 31, ty = threadIdx.x >> 5;
    int r0 = by * 32, c0 = bx * 32;
#pragma unroll
    for (int i = 0; i < 32; i += 8)
        tile[ty + i][tx] = in[(long)(r0 + ty + i) * C + c0 + tx];
    __syncthreads();
#pragma unroll
    for (int i = 0; i < 32; i += 8)
        out[(long)(c0 + ty + i) * R + r0 + tx] = (bf16)tile[tx][ty + i];
}

// ---------------- fused layernorms: rows 0..4095 -> x (DIM 1024); 4096..8191 -> xf (DIM 512) ----------------
__global__ __launch_bounds__(256) void ln_fused(
    const float* __restrict__ x, const float* __restrict__ xf,
    const float* __restrict__ g1, const float* __restrict__ b1,
    const float* __restrict__ g2, const float* __restrict__ b2,
    bf16* __restrict__ xn, bf16* __restrict__ xfn)
{
    long row = blockIdx.x;
    __shared__ float red[2][4];
    int w = threadIdx.x >> 6;
    if (row < 4096) {
        const float4* x4 = (const float4*)(x + row * 1024);
        float4 v = x4[threadIdx.x];
        float s = v.x + v.y + v.z + v.w;
        float s2 = v.x*v.x + v.y*v.y + v.z*v.z + v.w*v.w;
#pragma unroll
        for (int o = 32; o; o >>= 1) { s += __shfl_xor(s, o); s2 += __shfl_xor(s2, o); }
        if ((threadIdx.x & 63) == 0) { red[0][w] = s; red[1][w] = s2; }
        __syncthreads();
        s = red[0][0] + red[0][1] + red[0][2] + red[0][3];
        s2 = red[1][0] + red[1][1] + red[1][2] + red[1][3];
        float mean = s * (1.f / 1024.f);
        float rstd = rsqrtf(s2 * (1.f / 1024.f) - mean * mean + 1e-5f);
        int c = threadIdx.x * 4;
        float4 gg = *(const float4*)(g1 + c);
        float4 bb = *(const float4*)(b1 + c);
        bf16x4 ov;
        ov[0] = (bf16)((v.x - mean) * rstd * gg.x + bb.x);
        ov[1] = (bf16)((v.y - mean) * rstd * gg.y + bb.y);
        ov[2] = (bf16)((v.z - mean) * rstd * gg.z + bb.z);
        ov[3] = (bf16)((v.w - mean) * rstd * gg.w + bb.w);
        *(bf16x4*)(xn + row * 1024 + c) = ov;
    } else {
        long r2 = row - 4096;
        const float2* x2 = (const float2*)(xf + r2 * 512);
        float2 v = x2[threadIdx.x];
        float s = v.x + v.y;
        float s2 = v.x*v.x + v.y*v.y;
#pragma unroll
        for (int o = 32; o; o >>= 1) { s += __shfl_xor(s, o); s2 += __shfl_xor(s2, o); }
        if ((threadIdx.x & 63) == 0) { red[0][w] = s; red[1][w] = s2; }
        __syncthreads();
        s = red[0][0] + red[0][1] + red[0][2] + red[0][3];
        s2 = red[1][0] + red[1][1] + red[1][2] + red[1][3];
        float mean = s * (1.f / 512.f);
        float rstd = rsqrtf(s2 * (1.f / 512.f) - mean * mean + 1e-5f);
        int c = threadIdx.x * 2;
        float2 gg = *(const float2*)(g2 + c);
        float2 bb = *(const float2*)(b2 + c);
        bf16x2 ov;
        ov[0] = (bf16)((v.x - mean) * rstd * gg.x + bb.x);
        ov[1] = (bf16)((v.y - mean) * rstd * gg.y + bb.y);
        *(bf16x2*)(xfn + r2 * 512 + c) = ov;
    }
}

// ---------------- mask all-ones flags per (b, qtile64, ktile64) ----------------
__global__ __launch_bounds__(256) void mask_flags(
    const float* __restrict__ mask, unsigned char* __restrict__ flags)
{
    int blk = blockIdx.x;                  // b*256 + qt*16 + kt
    int b = blk >> 8, qt = (blk >> 4) & 15, kt = blk & 15;
    const float* src = mask + ((long)(b * 1024 + qt * 64 + (threadIdx.x >> 2))) * 1024
                     + kt * 64 + (threadIdx.x & 3) * 16;
    int ok = 1;
#pragma unroll
    for (int u = 0; u < 16; u += 4) {
        float4 v = *(const float4*)(src + u);
        ok &= (v.x == 1.f) & (v.y == 1.f) & (v.z == 1.f) & (v.w == 1.f);
    }
    ok = __syncthreads_and(ok);
    if (threadIdx.x == 0) flags[blk] = (unsigned char)ok;
}

// ---------------- adaln: silu(emb) @ emb_W + emb_b -> (B, 2048) fp32 ----------------
__global__ __launch_bounds__(256) void adaln_gemm2(
    const float* __restrict__ emb, const float* __restrict__ W,
    const float* __restrict__ eb, float* __restrict__ emo)
{
    __shared__ float es[1024];
    __shared__ float part[4][64];
    int b = blockIdx.y, t = threadIdx.x;
    int kg = t >> 6, c = t & 63;
    int col = blockIdx.x * 64 + c;
    for (int i = t; i < 1024; i += 256) {
        float e = emb[b * 1024 + i];
        es[i] = e / (1.f + expf(-e));
    }
    __syncthreads();
    float acc = 0.f;
    const float* wp = W + (long)(kg * 256) * 2048 + col;
    const float* ep = es + kg * 256;
#pragma unroll 4
    for (int k = 0; k < 256; ++k) acc += ep[k] * wp[(long)k * 2048];
    part[kg][c] = acc;
    __syncthreads();
    if (t < 64) {
        int col0 = blockIdx.x * 64 + t;
        emo[b * 2048 + col0] = part[0][t] + part[1][t] + part[2][t] + part[3][t] + eb[col0];
    }
}

// ---------------- GEMM core: 64x128 tile, BK=64, double-buffered LDS, counted vmcnt ----------------
// A(MxK) bf16 RM @ Bt(NxK) bf16 RM + bias. LDS chunk-XOR swizzle: LDS pos chunk p of row r
// holds global chunk p^(r&7) (baked into glds SOURCE; fragment reads apply same XOR).
template<int OUT_MODE>
__device__ __forceinline__ void gemm_core(
    const bf16* __restrict__ A, const bf16* __restrict__ Bt,
    const float* __restrict__ bias, const float* __restrict__ resid,
    void* __restrict__ outp, int N, int K, int brow, int bcol,
    bf16* As, bf16* Bs)
{
    const int t = threadIdx.x;
    const int wave = t >> 6, lane = t & 63;
    const int wr = wave & 1, wc = wave >> 1;
    const int l3 = lane >> 3, l7 = lane & 7;
    const int swz = (l7 ^ (l3 & 7)) * 8;     // source chunk offset (elems)
    const bf16* aS = A  + (long)(brow + wave * 8 + l3) * K + swz;
    const bf16* bS = Bt + (long)(bcol + wave * 8 + l3) * K + swz;
    char* aD = (char*)As + wave * 1024;      // + bsel*8192  + p*4096
    char* bD = (char*)Bs + wave * 1024;      // + bsel*16384 + p*4096
    const int fr = lane & 15, la = lane >> 4;
    // fragment elem offsets: row*64 + ((kk*4+la)^(fr&7))*8
    int afOff[2][2], bfOff[4][2];
#pragma unroll
    for (int m = 0; m < 2; ++m)
#pragma unroll
        for (int kk = 0; kk < 2; ++kk)
            afOff[m][kk] = (wr * 32 + m * 16 + fr) * 64 + (((kk * 4 + la) ^ (fr & 7)) * 8);
#pragma unroll
    for (int n = 0; n < 4; ++n)
#pragma unroll
        for (int kk = 0; kk < 2; ++kk)
            bfOff[n][kk] = (wc * 64 + n * 16 + fr) * 64 + (((kk * 4 + la) ^ (fr & 7)) * 8);

    const int nt = K >> 6;
    f32x4 acc[2][4] = {};

#define G_STAGE(TI, BSEL) do {                                                       \
        long k0 = (long)(TI) * 64;                                                   \
        _Pragma("unroll")                                                            \
        for (int p = 0; p < 2; ++p)                                                  \
            __builtin_amdgcn_global_load_lds(AS1C(aS + k0 + (long)p * 32 * K),       \
                AS3(aD + (BSEL) * 8192 + p * 4096), 16, 0, 0);                       \
        _Pragma("unroll")                                                            \
        for (int p = 0; p < 4; ++p)                                                  \
            __builtin_amdgcn_global_load_lds(AS1C(bS + k0 + (long)p * 32 * K),       \
                AS3(bD + (BSEL) * 16384 + p * 4096), 16, 0, 0);                      \
    } while (0)

    G_STAGE(0, 0);
    int cur = 0;
    for (int ti = 0; ti < nt; ++ti) {
        if (ti + 1 < nt) {
            G_STAGE(ti + 1, cur ^ 1);
            asm volatile("s_waitcnt vmcnt(6)" ::: "memory");
        } else {
            asm volatile("s_waitcnt vmcnt(0)" ::: "memory");
        }
        __builtin_amdgcn_s_barrier();
        const bf16* ab = As + cur * 4096;
        const bf16* bb = Bs + cur * 8192;
        bf16x8 af[2][2], bf_[4][2];
#pragma unroll
        for (int m = 0; m < 2; ++m)
#pragma unroll
            for (int kk = 0; kk < 2; ++kk)
                af[m][kk] = *(const bf16x8*)&ab[afOff[m][kk]];
#pragma unroll
        for (int n = 0; n < 4; ++n)
#pragma unroll
            for (int kk = 0; kk < 2; ++kk)
                bf_[n][kk] = *(const bf16x8*)&bb[bfOff[n][kk]];
        __builtin_amdgcn_s_setprio(1);
#pragma unroll
        for (int kk = 0; kk < 2; ++kk)
#pragma unroll
            for (int m = 0; m < 2; ++m)
#pragma unroll
                for (int n = 0; n < 4; ++n)
                    acc[m][n] = __builtin_amdgcn_mfma_f32_16x16x32_bf16(af[m][kk], bf_[n][kk], acc[m][n], 0, 0, 0);
        __builtin_amdgcn_s_setprio(0);
        __builtin_amdgcn_s_barrier();
        cur ^= 1;
    }
#undef G_STAGE

    const int er = la * 4, ec = fr;
    if constexpr (OUT_MODE == 0) {
        bf16* C = (bf16*)outp;
#pragma unroll
        for (int n = 0; n < 4; ++n) {
            int col = bcol + wc * 64 + n * 16 + ec;
            float bcv = bias[col];
#pragma unroll
            for (int m = 0; m < 2; ++m) {
                long rbase = (long)(brow + wr * 32 + m * 16 + er) * N + col;
#pragma unroll
                for (int j = 0; j < 4; ++j)
                    C[rbase + (long)j * N] = (bf16)(acc[m][n][j] + bcv);
            }
        }
    } else {
        float* C = (float*)outp;
#pragma unroll
        for (int n = 0; n < 4; ++n) {
            int col = bcol + wc * 64 + n * 16 + ec;
            float bcv = bias[col];
#pragma unroll
            for (int m = 0; m < 2; ++m) {
                long rbase = (long)(brow + wr * 32 + m * 16 + er) * N + col;
#pragma unroll
                for (int j = 0; j < 4; ++j) {
                    long idx = rbase + (long)j * N;
                    C[idx] = resid[idx] + acc[m][n][j] + bcv;
                }
            }
        }
    }
}

// fused Q + KV projection GEMMs: blocks 0..511 -> Q (N=1024,K=1024); 512..1535 -> KV (N=2048,K=512)
__global__ __launch_bounds__(256) void qkv_gemm(
    const bf16* __restrict__ xn, const bf16* __restrict__ WqT, const float* __restrict__ bq,
    bf16* __restrict__ qb,
    const bf16* __restrict__ xfn, const bf16* __restrict__ WkvT, const float* __restrict__ bkv,
    bf16* __restrict__ kvb)
{
    __shared__ __align__(16) bf16 As[2 * 4096];
    __shared__ __align__(16) bf16 Bs[2 * 8192];
    int f = blockIdx.x;
    if (f < 512)
        gemm_core<0>(xn, WqT, bq, nullptr, qb, 1024, 1024, (f >> 3) * 64, (f & 7) * 128, As, Bs);
    else {
        int g = f - 512;
        gemm_core<0>(xfn, WkvT, bkv, nullptr, kvb, 2048, 512, (g >> 4) * 64, (g & 15) * 128, As, Bs);
    }
}

template<int OUT_MODE>
__global__ __launch_bounds__(256) void gemm_dbuf(
    const bf16* __restrict__ A, const bf16* __restrict__ Bt,
    const float* __restrict__ bias, const float* __restrict__ resid,
    void* __restrict__ outp, int N, int K)
{
    __shared__ __align__(16) bf16 As[2 * 4096];
    __shared__ __align__(16) bf16 Bs[2 * 8192];
    gemm_core<OUT_MODE>(A, Bt, bias, resid, outp, N, K, blockIdx.y * 64, blockIdx.x * 128, As, Bs);
}

// ---------------- V transpose into swizzle-baked tiles ----------------
// vt[bh][kvt][d(64)][c(8)][j(8)] with tile[d][c] = V[key=8*(c^phi(d))+j][d]; phi(d)=(d&3)|(((d>>3)&1)<<2)
__global__ __launch_bounds__(256) void vtrans(
    const bf16* __restrict__ kvb, bf16* __restrict__ vt)
{
    __shared__ bf16 tile[64 * 72];
    int kvt = blockIdx.x, bh = blockIdx.y;
    int b = bh >> 4, h = bh & 15;
    int t = threadIdx.x;
    {
        int key = t >> 2, d0 = (t & 3) * 16;
        const bf16* src = kvb + (long)(b * 1024 + kvt * 64 + key) * 2048 + 1024 + h * 64 + d0;
        bf16x8 v0 = *(const bf16x8*)src;
        bf16x8 v1 = *(const bf16x8*)(src + 8);
        *(bf16x8*)&tile[key * 72 + d0] = v0;
        *(bf16x8*)&tile[key * 72 + d0 + 8] = v1;
    }
    __syncthreads();
    bf16* vtile = vt + ((long)(bh * 16 + kvt)) * 4096;
    int d = t >> 2;
    int phi = (d & 3) | (((d >> 3) & 1) << 2);
#pragma unroll
    for (int half = 0; half < 2; ++half) {
        int c = (t & 3) + half * 4;
        int key8 = 8 * (c ^ phi);
        bf16x8 w;
#pragma unroll
        for (int j = 0; j < 8; ++j) w[j] = tile[(key8 + j) * 72 + d];
        *(bf16x8*)&vtile[d * 64 + c * 8] = w;
    }
}

// ---------------- flash attention: swapped QK^T, dbuf LDS, counted vmcnt, defer-max ----------------
__global__ __launch_bounds__(256, 4) void flash3(
    const bf16* __restrict__ Q, const bf16* __restrict__ KV, const bf16* __restrict__ VT,
    const float* __restrict__ mask, const unsigned char* __restrict__ flags,
    bf16* __restrict__ Y)
{
    const int f = blockIdx.x;
    const int bh = f & 63;                 // 8 distinct bh per XCD -> KV fits L2
    const int qt = f >> 6;
    const int b = bh >> 4, h = bh & 15;
    const int t = threadIdx.x, wave = t >> 6, lane = t & 63;
    const int la = lane >> 4, lb = lane & 15;

    __shared__ __align__(16) bf16 Ks[2][64 * 64];
    __shared__ __align__(16) bf16 Vs[2][64 * 64];

    const int qrow = qt * 64 + wave * 16;
    bf16x8 qf0, qf1;
    {
        const bf16* qp = Q + (long)(b * 1024 + qrow + lb) * 1024 + h * 64 + la * 8;
        qf0 = *(const bf16x8*)qp;
        qf1 = *(const bf16x8*)(qp + 32);
    }
    f32x4 o[4] = {};
    float m_run = -3e38f, l_run = 0.f;
    const float CL = 0.125f * 1.44269504f;

    const int srow = lane >> 3, sc = lane & 7;
    const int phiS = (srow & 3) | ((wave & 1) << 2);
    const bf16* kS = KV + (long)(b * 1024 + wave * 8 + srow) * 2048 + h * 64 + ((sc ^ phiS) * 8);
    const bf16* vS = VT + (long)(bh * 16) * 4096 + wave * 512 + lane * 8;
    char* kD0 = (char*)Ks + wave * 1024;
    char* vD0 = (char*)Vs + wave * 1024;

    const int phiK = (lb & 3) | (((lb >> 2) & 1) << 2);
    const int phiV = (lb & 3) | (((lb >> 3) & 1) << 2);
    const int rbase = (lb >> 2) * 8 + (lb & 3);
    const int kOff0 = rbase * 64 + ((la ^ phiK) * 8);
    const int kOff1 = rbase * 64 + (((4 + la) ^ phiK) * 8);
    const int vOff0 = lb * 64 + ((la ^ phiV) * 8);
    const int vOff1 = lb * 64 + (((4 + la) ^ phiV) * 8);
    const int rowoff[4] = {0, 2048, 256, 2304};

    // preload flags to keep the loop free of stray VMEM (vmcnt counting)
    const unsigned char* flagrow = flags + b * 256 + qt * 16;
    unsigned fl = 0;
#pragma unroll
    for (int i = 0; i < 16; ++i) fl |= ((unsigned)flagrow[i]) << i;
    const float* mrow_p = mask + (long)(b * 1024 + qrow + lb) * 1024;

    asm volatile("s_waitcnt vmcnt(0)" ::: "memory");   // drain Q/flag loads before counting

#define F_STAGE(KVI, BSEL) do {                                                        \
        const long key0_ = (long)(KVI) * 64;                                           \
        __builtin_amdgcn_global_load_lds(AS1C(kS + key0_ * 2048),                      \
            AS3(kD0 + (BSEL) * 8192), 16, 0, 0);                                       \
        __builtin_amdgcn_global_load_lds(AS1C(kS + (key0_ + 32) * 2048),               \
            AS3(kD0 + (BSEL) * 8192 + 4096), 16, 0, 0);                                \
        __builtin_amdgcn_global_load_lds(AS1C(vS + (KVI) * 4096),                      \
            AS3(vD0 + (BSEL) * 8192), 16, 0, 0);                                       \
        __builtin_amdgcn_global_load_lds(AS1C(vS + (KVI) * 4096 + 2048),               \
            AS3(vD0 + (BSEL) * 8192 + 4096), 16, 0, 0);                                \
    } while (0)

    F_STAGE(0, 0);
    int cur = 0;
    for (int kv = 0; kv < 16; ++kv) {
        if (kv < 15) {
            F_STAGE(kv + 1, cur ^ 1);
            asm volatile("s_waitcnt vmcnt(4)" ::: "memory");
        } else {
            asm volatile("s_waitcnt vmcnt(0)" ::: "memory");
        }
        __builtin_amdgcn_s_barrier();
        const bf16* kb = &Ks[cur][0];
        const bf16* vb = &Vs[cur][0];

        // S^T = K Q^T : lane holds S[key=(n&1)*32+la*8+(n>>1)*4+r][q=lb]
        f32x4 s[4] = {};
        __builtin_amdgcn_s_setprio(1);
#pragma unroll
        for (int n = 0; n < 4; ++n) {
            s[n] = __builtin_amdgcn_mfma_f32_16x16x32_bf16(*(const bf16x8*)(kb + kOff0 + rowoff[n]), qf0, s[n], 0, 0, 0);
            s[n] = __builtin_amdgcn_mfma_f32_16x16x32_bf16(*(const bf16x8*)(kb + kOff1 + rowoff[n]), qf1, s[n], 0, 0, 0);
        }
        __builtin_amdgcn_s_setprio(0);

        if (!((fl >> kv) & 1)) {   // mask in raw-score units (x8)
            const int key0 = kv * 64;
#pragma unroll
            for (int n = 0; n < 4; ++n)
#pragma unroll
                for (int r = 0; r < 4; ++r) {
                    int key = (n & 1) * 32 + la * 8 + (n >> 1) * 4 + r;
                    s[n][r] += (1.f - mrow_p[key0 + key]) * -800000.f;
                }
        }

        // online softmax with defer-max (rescale only when max grows past THR=64 raw)
        float t0 = fmaxf(fmaxf(s[0][0], s[0][1]), fmaxf(s[0][2], s[0][3]));
        float t1 = fmaxf(fmaxf(s[1][0], s[1][1]), fmaxf(s[1][2], s[1][3]));
        float t2 = fmaxf(fmaxf(s[2][0], s[2][1]), fmaxf(s[2][2], s[2][3]));
        float t3 = fmaxf(fmaxf(s[3][0], s[3][1]), fmaxf(s[3][2], s[3][3]));
        float tmax = fmaxf(fmaxf(t0, t1), fmaxf(t2, t3));
        tmax = fmaxf(tmax, __shfl_xor(tmax, 16));
        tmax = fmaxf(tmax, __shfl_xor(tmax, 32));
        if (!__all(tmax - m_run <= 64.f)) {
            float mnew = fmaxf(m_run, tmax);
            float al = exp2f((m_run - mnew) * CL);
            l_run *= al;
#pragma unroll
            for (int d = 0; d < 4; ++d)
#pragma unroll
                for (int j = 0; j < 4; ++j) o[d][j] *= al;
            m_run = mnew;
        }
        float p[4][4];
        float rsum = 0.f;
#pragma unroll
        for (int n = 0; n < 4; ++n)
#pragma unroll
            for (int r = 0; r < 4; ++r) {
                p[n][r] = exp2f((s[n][r] - m_run) * CL);
                rsum += p[n][r];
            }
        rsum += __shfl_xor(rsum, 16);
        rsum += __shfl_xor(rsum, 32);
        l_run += rsum;

        // P -> B-frags (register packing only)
        bf16x8 pb0, pb1;
#pragma unroll
        for (int j = 0; j < 4; ++j) {
            pb0[j] = (bf16)p[0][j]; pb0[j + 4] = (bf16)p[2][j];
            pb1[j] = (bf16)p[1][j]; pb1[j + 4] = (bf16)p[3][j];
        }

        // O^T += V^T P
        __builtin_amdgcn_s_setprio(1);
#pragma unroll
        for (int d = 0; d < 4; ++d) {
            o[d] = __builtin_amdgcn_mfma_f32_16x16x32_bf16(*(const bf16x8*)(vb + vOff0 + d * 1024), pb0, o[d], 0, 0, 0);
            o[d] = __builtin_amdgcn_mfma_f32_16x16x32_bf16(*(const bf16x8*)(vb + vOff1 + d * 1024), pb1, o[d], 0, 0, 0);
        }
        __builtin_amdgcn_s_setprio(0);
        __builtin_amdgcn_s_barrier();
        cur ^= 1;
    }
#undef F_STAGE

    float inv = 1.f / l_run;
    bf16* yp = Y + (long)(b * 1024 + qrow + lb) * 1024 + h * 64 + la * 4;
#pragma unroll
    for (int d = 0; d < 4; ++d) {
        bf16x4 yv;
#pragma unroll
        for (int j = 0; j < 4; ++j) yv[j] = (bf16)(o[d][j] * inv);
        *(bf16x4*)(yp + d * 16) = yv;
    }
}

// ---------------- LN(y)*(1+scale)+shift -> silu -> bf16 ----------------
__global__ __launch_bounds__(256) void ln_mod_silu(
    const bf16* __restrict__ Yin, const float* __restrict__ g, const float* __restrict__ bb,
    const float* __restrict__ emo, bf16* __restrict__ act)
{
    long row = blockIdx.x;
    int b = (int)(row >> 10);
    const bf16* y = Yin + row * 1024;
    int c = threadIdx.x * 4;
    bf16x4 yv = *(const bf16x4*)(y + c);
    float v0 = (float)yv[0], v1 = (float)yv[1], v2 = (float)yv[2], v3 = (float)yv[3];
    float s = v0 + v1 + v2 + v3, s2 = v0*v0 + v1*v1 + v2*v2 + v3*v3;
#pragma unroll
    for (int o = 32; o; o >>= 1) { s += __shfl_xor(s, o); s2 += __shfl_xor(s2, o); }
    __shared__ float red[2][4];
    int w = threadIdx.x >> 6;
    if ((threadIdx.x & 63) == 0) { red[0][w] = s; red[1][w] = s2; }
    __syncthreads();
    s = red[0][0] + red[0][1] + red[0][2] + red[0][3];
    s2 = red[1][0] + red[1][1] + red[1][2] + red[1][3];
    float mean = s * (1.f / 1024.f);
    float rstd = rsqrtf(s2 * (1.f / 1024.f) - mean * mean + 1e-5f);
    float4 gg = *(const float4*)(g + c);
    float4 bv = *(const float4*)(bb + c);
    float4 scv = *(const float4*)(emo + b * 2048 + c);
    float4 shv = *(const float4*)(emo + b * 2048 + 1024 + c);
    float hv[4];
    hv[0] = ((v0 - mean) * rstd * gg.x + bv.x) * (1.f + scv.x) + shv.x;
    hv[1] = ((v1 - mean) * rstd * gg.y + bv.y) * (1.f + scv.y) + shv.y;
    hv[2] = ((v2 - mean) * rstd * gg.z + bv.z) * (1.f + scv.z) + shv.z;
    hv[3] = ((v3 - mean) * rstd * gg.w + bv.w) * (1.f + scv.w) + shv.w;
    bf16x4 ov;
#pragma unroll
    for (int j = 0; j < 4; ++j) ov[j] = (bf16)(hv[j] / (1.f + expf(-hv[j])));
    *(bf16x4*)(act + row * 1024 + c) = ov;
}

extern "C" void kernel_launch(void* const* d_in, const int* in_sizes, int n_in,
                              void* d_out, int out_size, void* d_ws, size_t ws_size,
                              hipStream_t stream)
{
    const float* x     = (const float*)d_in[0];
    const float* xf    = (const float*)d_in[1];
    const float* emb   = (const float*)d_in[2];
    const float* mask  = (const float*)d_in[3];
    const float* ln_g  = (const float*)d_in[4];
    const float* ln_b  = (const float*)d_in[5];
    const float* aln_g = (const float*)d_in[6];
    const float* aln_b = (const float*)d_in[7];
    const float* n2_g  = (const float*)d_in[8];
    const float* n2_b  = (const float*)d_in[9];
    const float* Wq    = (const float*)d_in[10];
    const float* bq    = (const float*)d_in[11];
    const float* Wk    = (const float*)d_in[12];
    const float* bk    = (const float*)d_in[13];
    const float* Wv    = (const float*)d_in[14];
    const float* bv    = (const float*)d_in[15];
    const float* emb_W = (const float*)d_in[16];
    const float* emb_b = (const float*)d_in[17];
    const float* out_W = (const float*)d_in[18];
    const float* out_b = (const float*)d_in[19];
    float* out = (float*)d_out;

    char* w = (char*)d_ws;
    bf16* xn   = (bf16*)w; w += (size_t)4096 * 1024 * 2;   // 8 MB (reused: vt, then actb)
    bf16* xfn  = (bf16*)w; w += (size_t)4096 * 512 * 2;    // 4 MB
    bf16* WqT  = (bf16*)w; w += (size_t)1024 * 1024 * 2;   // 2 MB
    bf16* WkvT = (bf16*)w; w += (size_t)2048 * 512 * 2;    // 2 MB
    bf16* WoT  = (bf16*)w; w += (size_t)1024 * 1024 * 2;   // 2 MB
    bf16* qb   = (bf16*)w; w += (size_t)4096 * 1024 * 2;   // 8 MB
    bf16* kvb  = (bf16*)w; w += (size_t)4096 * 2048 * 2;   // 16 MB
    bf16* yb   = (bf16*)w; w += (size_t)4096 * 1024 * 2;   // 8 MB
    float* bkv = (float*)w; w += (size_t)2048 * 4;         // 8 KB
    float* emo = (float*)w; w += (size_t)4 * 2048 * 4;     // 32 KB
    unsigned char* flg = (unsigned char*)w;                // 1 KB
    bf16* vt   = xn;   // lifetimes stream-ordered: xn -> qkv_gemm; vt -> flash; actb -> out gemm
    bf16* actb = xn;

    prep<<<3080, 256, 0, stream>>>(Wq, Wk, Wv, out_W, bk, bv, WqT, WkvT, WoT, bkv);
    ln_fused<<<8192, 256, 0, stream>>>(x, xf, ln_g, ln_b, aln_g, aln_b, xn, xfn);
    mask_flags<<<1024, 256, 0, stream>>>(mask, flg);
    adaln_gemm2<<<dim3(32, 4), 256, 0, stream>>>(emb, emb_W, emb_b, emo);

    qkv_gemm<<<1536, 256, 0, stream>>>(xn, WqT, bq, qb, xfn, WkvT, bkv, kvb);
    vtrans<<<dim3(16, 64), 256, 0, stream>>>(kvb, vt);

    flash3<<<1024, 256, 0, stream>>>(qb, kvb, vt, mask, flg, yb);

    ln_mod_silu<<<4096, 256, 0, stream>>>(yb, n2_g, n2_b, emo, actb);
    gemm_dbuf<1><<<dim3(8, 64), 256, 0, stream>>>(actb, WoT, out_b, x, out, 1024, 1024);
}